// Round 13
// baseline (54.422 us; speedup 1.0000x reference)
//
#include <hip/hip_runtime.h>
#include <hip/hip_bf16.h>

#define HW 16384
#define W 128
#define C 128
#define HID 256

typedef __attribute__((ext_vector_type(8))) short short8v;
typedef __attribute__((ext_vector_type(4))) float f32x4;

#if defined(__has_builtin)
#if __has_builtin(__builtin_amdgcn_fdot2_f32_bf16)
#define HAVE_FDOT2 1
#endif
#endif
#ifndef HAVE_FDOT2
#define HAVE_FDOT2 0
#endif

#if HAVE_FDOT2
typedef __attribute__((ext_vector_type(2))) __bf16 bf16x2;
#endif

__device__ __forceinline__ unsigned short f2bf(float f) {
    union { float f; unsigned u; } x; x.f = f;
    unsigned r = x.u + 0x7FFF + ((x.u >> 16) & 1);
    return (unsigned short)(r >> 16);
}
__device__ __forceinline__ float bf2f(unsigned short b) {
    union { unsigned u; float f; } x; x.u = ((unsigned)b) << 16;
    return x.f;
}

// ---- async-stage split: issue 32KB panel (8 x 16B per thread) into regs ----
__device__ __forceinline__ void stage_load(const unsigned short* __restrict__ src,
                                           short8v* r, int t) {
    #pragma unroll
    for (int c = 0; c < 8; ++c)
        r[c] = *(const short8v*)(src + (size_t)(c * 256 + t) * 8);
}
// ---- commit regs to LDS, XOR-swizzled: granule col ^= (row&7). RSH=log2(granules/row)
template<int RSH>
__device__ __forceinline__ void stage_write(const short8v* r, unsigned short* lds, int t) {
    #pragma unroll
    for (int c = 0; c < 8; ++c) {
        int gi = c * 256 + t;
        int row = gi >> RSH, colg = gi & ((1 << RSH) - 1);
        *(short8v*)(lds + (size_t)(((row << RSH) + (colg ^ (row & 7))) << 3)) = r[c];
    }
}
// ---- stage a 32KB bf16 panel directly from an f32 weight matrix (converting) ----
template<int RSH>
__device__ __forceinline__ void stage32f(const float* __restrict__ src,
                                         unsigned short* lds, int t) {
    #pragma unroll
    for (int c = 0; c < 8; ++c) {
        int gi = c * 256 + t;
        int row = gi >> RSH, colg = gi & ((1 << RSH) - 1);
        float4 a = *(const float4*)(src + (size_t)gi * 8);
        float4 b = *(const float4*)(src + (size_t)gi * 8 + 4);
        short8v v;
        v[0] = (short)f2bf(a.x); v[1] = (short)f2bf(a.y);
        v[2] = (short)f2bf(a.z); v[3] = (short)f2bf(a.w);
        v[4] = (short)f2bf(b.x); v[5] = (short)f2bf(b.y);
        v[6] = (short)f2bf(b.z); v[7] = (short)f2bf(b.w);
        *(short8v*)(lds + (size_t)(((row << RSH) + (colg ^ (row & 7))) << 3)) = v;
    }
}

// ---------------- kernel 1: q/k/v 1x1 convs via MFMA; also converts mlp weights ----------------
// 512 blocks x 256 thr; 32 px/block. Weight panels staged+converted from f32.
// Input staging float4-vectorized (12 wide loads/thread instead of 48 dwords).
__global__ __launch_bounds__(256, 2)
void qkv_mfma(const float* __restrict__ q_in, const float* __restrict__ k_in,
              const float* __restrict__ v_in,
              const float* __restrict__ w_q, const float* __restrict__ w_k,
              const float* __restrict__ w_v,
              const float* __restrict__ wfc, const float* __restrict__ w1,
              const float* __restrict__ w2,
              unsigned short* __restrict__ wb,
              unsigned short* __restrict__ q_t, unsigned short* __restrict__ kv_t) {
    __shared__ unsigned short lx[3][32 * 128];   // 24 KB inputs (pixel-swizzled)
    __shared__ unsigned short wbuf[16384];       // 32 KB weight panel
    const int t = threadIdx.x;
    const int p0 = blockIdx.x * 32;
    const int lane = t & 63, row16 = lane & 15, g = lane >> 4;
    const int w = t >> 6, nh = w & 1, mh = w >> 1;
    const int ploc = nh * 16 + row16;
    const int pix = p0 + ploc;
    const int swz = (ploc & 7) << 3;

    stage32f<4>(w_q, wbuf, t);    // wq panel, in flight during x-tile conversion

    // side job: convert mlp weights (98304 f32) spread across 512 blocks
    if (t < 192) {
        int i = blockIdx.x * 192 + t;
        float v = (i < 16384) ? wfc[i] : (i < 49152) ? w1[i - 16384] : w2[i - 49152];
        wb[i] = f2bf(v);
    }

    const float* ins[3] = {q_in, k_in, v_in};
    #pragma unroll
    for (int m = 0; m < 3; ++m) {
        #pragma unroll
        for (int i = 0; i < 4; ++i) {
            int fid = t + 256 * i;          // 0..1023
            int c = fid >> 3;               // channel 0..127
            int p4 = (fid & 7) << 2;        // pixel group 0,4,...,28
            float4 v = *(const float4*)&ins[m][c * HW + p0 + p4];
            #pragma unroll
            for (int j = 0; j < 4; ++j) {
                int p = p4 + j;
                float vv = j == 0 ? v.x : j == 1 ? v.y : j == 2 ? v.z : v.w;
                lx[m][p * 128 + (c ^ ((p & 7) << 3))] = f2bf(vv);
            }
        }
    }

    const float* ws[3] = {w_q, w_k, w_v};
    #pragma unroll 1
    for (int m = 0; m < 3; ++m) {
        if (m > 0) {
            __syncthreads();               // previous GEMM done reading wbuf
            stage32f<4>(ws[m], wbuf, t);
        }
        __syncthreads();                   // staging (and lx on m=0) visible

        f32x4 acc[4] = {};
        #pragma unroll
        for (int kk = 0; kk < 4; ++kk) {
            short8v b = *(const short8v*)&lx[m][ploc * 128 + ((kk * 32 + g * 8) ^ swz)];
            #pragma unroll
            for (int f = 0; f < 4; ++f) {
                int row = mh * 64 + f * 16 + row16;
                short8v a = *(const short8v*)&wbuf[(row << 7) + (((kk * 4 + g) ^ (row & 7)) << 3)];
                acc[f] = __builtin_amdgcn_mfma_f32_16x16x32_bf16(a, b, acc[f], 0, 0, 0);
            }
        }
        #pragma unroll
        for (int f = 0; f < 4; ++f) {
            int o = mh * 64 + f * 16 + g * 4;
            ushort4 st;
            st.x = f2bf(acc[f][0]); st.y = f2bf(acc[f][1]);
            st.z = f2bf(acc[f][2]); st.w = f2bf(acc[f][3]);
            if (m == 0)      *(ushort4*)&q_t[(size_t)pix * 128 + o] = st;
            else if (m == 1) *(ushort4*)&kv_t[(size_t)pix * 256 + o] = st;
            else             *(ushort4*)&kv_t[(size_t)pix * 256 + 128 + o] = st;
        }
    }
}

// ---------------- kernel 2: deformable attention, factorized 6x6 corner grid ----------------
// bf16 q/kv, 16B gathers: 16 thr/px, 8 ch/thr, 16 px/block. 1024 blocks.
// Phase A uses v_dot2_f32_bf16 when available (4 insts per 8-ch partial dot).
__global__ __launch_bounds__(256, 2)
void attn_kernel(const unsigned short* __restrict__ q_t, const unsigned short* __restrict__ kv_t,
                 const float* __restrict__ deform, unsigned short* __restrict__ ao_t) {
    const int t = threadIdx.x;
    const int pi = t >> 4;     // pixel within block (16)
    const int g = t & 15;      // channel group (8 ch = 16 B)
    const char* kvb = (const char*)kv_t;
    const int go = g * 16;

    const int jj = blockIdx.x;
    const int y = jj >> 3;
    const int x = ((jj & 7) << 4) + pi;
    const int pix = y * W + x;

    const float dx = deform[pix];
    const float dy = deform[HW + pix];
    const float fdx = floorf(dx), fdy = floorf(dy);
    const float fx = dx - fdx, fy = dy - fdy;
    const float wx0 = 1.f - fx, wx1 = fx, wy0 = 1.f - fy, wy1 = fy;
    const int x0 = x - 2 + (int)fdx;
    const int y0 = y - 2 + (int)fdy;

    int   coff[6], roff[6];
    float colv[6], rowv[6];
    #pragma unroll
    for (int j = 0; j < 6; ++j) {
        int xc = x0 + j, yc = y0 + j;
        colv[j] = ((unsigned)xc <= 127u) ? 1.f : 0.f;
        rowv[j] = ((unsigned)yc <= 127u) ? 1.f : 0.f;
        coff[j] = (min(max(xc, 0), 127) << 9) + go;   // x*512B + channel byte off
        roff[j] = min(max(yc, 0), 127) << 16;         // y*64KB
    }

#if HAVE_FDOT2
    union QU { unsigned short u[8]; bf16x2 b[4]; } qu;
    {
        short8v qv = *(const short8v*)(q_t + (size_t)pix * C + g * 8);
        #pragma unroll
        for (int e = 0; e < 8; ++e)
            qu.u[e] = f2bf(bf2f((unsigned short)qv[e]) * 0.25f);   // *0.25 exact in bf16
    }
#else
    float q[8];
    {
        short8v qv = *(const short8v*)(q_t + (size_t)pix * C + g * 8);
        #pragma unroll
        for (int e = 0; e < 8; ++e) q[e] = bf2f((unsigned short)qv[e]) * 0.25f;
    }
#endif

    // ---- phase A: 36 per-thread partial dots (16B k loads) ----
    float d[36];
    #pragma unroll
    for (int jy = 0; jy < 6; ++jy) {
        #pragma unroll
        for (int jx = 0; jx < 6; ++jx) {
            short8v k = *(const short8v*)(kvb + (roff[jy] + coff[jx]));
#if HAVE_FDOT2
            union KU { short8v s; bf16x2 b[4]; } ku;
            ku.s = k;
            float dd = 0.f;
            dd = __builtin_amdgcn_fdot2_f32_bf16(ku.b[0], qu.b[0], dd, false);
            dd = __builtin_amdgcn_fdot2_f32_bf16(ku.b[1], qu.b[1], dd, false);
            dd = __builtin_amdgcn_fdot2_f32_bf16(ku.b[2], qu.b[2], dd, false);
            dd = __builtin_amdgcn_fdot2_f32_bf16(ku.b[3], qu.b[3], dd, false);
#else
            float dd = 0.f;
            #pragma unroll
            for (int e = 0; e < 8; ++e) dd += q[e] * bf2f((unsigned short)k[e]);
#endif
            d[jy * 6 + jx] = dd * (rowv[jy] * colv[jx]);
        }
    }

    // ---- scores: bilinear combine + head reduce (2 lanes/head) ----
    float s[25];
    #pragma unroll
    for (int iy = 0; iy < 5; ++iy) {
        #pragma unroll
        for (int ix = 0; ix < 5; ++ix) {
            float sp = wy0 * (wx0 * d[iy * 6 + ix]       + wx1 * d[iy * 6 + ix + 1])
                     + wy1 * (wx0 * d[(iy + 1) * 6 + ix] + wx1 * d[(iy + 1) * 6 + ix + 1]);
            sp += __shfl_xor(sp, 1);     // 2 threads = one 16-ch head
            s[iy * 5 + ix] = sp;
        }
    }

    // ---- softmax over 25 (in registers) ----
    float m = s[0];
    #pragma unroll
    for (int p = 1; p < 25; ++p) m = fmaxf(m, s[p]);
    float sum = 0.f;
    #pragma unroll
    for (int p = 0; p < 25; ++p) {
        float e = __expf(s[p] - m);
        s[p] = e;
        sum += e;
    }
    const float inv = 1.f / sum;

    // ---- corner weights: transpose bilinear of probs, fold validity ----
    float b[36];
    #pragma unroll
    for (int jy = 0; jy < 6; ++jy) {
        #pragma unroll
        for (int jx = 0; jx < 6; ++jx) {
            float acc = 0.f;
            if (jy < 5  && jx < 5)  acc += wy0 * wx0 * s[jy * 5 + jx];
            if (jy < 5  && jx >= 1) acc += wy0 * wx1 * s[jy * 5 + jx - 1];
            if (jy >= 1 && jx < 5)  acc += wy1 * wx0 * s[(jy - 1) * 5 + jx];
            if (jy >= 1 && jx >= 1) acc += wy1 * wx1 * s[(jy - 1) * 5 + jx - 1];
            b[jy * 6 + jx] = acc * (rowv[jy] * colv[jx]);
        }
    }

    // ---- phase B: 36 V gathers (16B) ----
    float oc[8] = {0.f, 0.f, 0.f, 0.f, 0.f, 0.f, 0.f, 0.f};
    #pragma unroll
    for (int jy = 0; jy < 6; ++jy) {
        #pragma unroll
        for (int jx = 0; jx < 6; ++jx) {
            short8v v = *(const short8v*)(kvb + (roff[jy] + coff[jx]) + 256);
            float bw = b[jy * 6 + jx];
            #pragma unroll
            for (int e = 0; e < 8; ++e) oc[e] += bw * bf2f((unsigned short)v[e]);
        }
    }

    short8v ob;
    #pragma unroll
    for (int e = 0; e < 8; ++e) ob[e] = (short)f2bf(oc[e] * inv);
    *(short8v*)(ao_t + (size_t)pix * C + g * 8) = ob;
}

// ---------------- kernel 3: fc + MLP + residual + stats via MFMA ----------------
// 512 blocks x 256 thr, 32 px/block; 56KB LDS -> 2 blocks/CU so one block's
// staging hides under the other's MFMA. Pipelined weight staging as before.
__global__ __launch_bounds__(256, 2)
void mlp_mfma(const unsigned short* __restrict__ ao_t, const unsigned short* __restrict__ wb,
              const float* __restrict__ b1, const float* __restrict__ b2,
              float* __restrict__ out2, float2* __restrict__ partials) {
    __shared__ unsigned short wbuf[16384];    // 32 KB weight panel
    __shared__ unsigned short l1[32 * 128];   // out1 bf16 (pixel-swizzled)   8 KB
    __shared__ unsigned short lh[32 * 256];   // hid  bf16 (pixel-swizzled)  16 KB
    __shared__ float rs[8];
    const int t = threadIdx.x;
    const int p0 = blockIdx.x * 32;
    const int lane = t & 63, row16 = lane & 15, g = lane >> 4;
    const int w = t >> 6, nh = w & 1, mh = w >> 1;
    const int ploc = nh * 16 + row16;
    const int pix = p0 + ploc;
    const int swz = (ploc & 7) << 3;
    const unsigned short* wfc_b = wb;
    const unsigned short* w1_b  = wb + 16384;
    const unsigned short* w2_b  = wb + 49152;

    short8v r[8];
    stage_load(wfc_b, r, t);
    // B-fragments for GEMM1 issued early too
    short8v bf[4];
    #pragma unroll
    for (int kk = 0; kk < 4; ++kk)
        bf[kk] = *(const short8v*)&ao_t[(size_t)pix * 128 + kk * 32 + g * 8];
    stage_write<4>(r, wbuf, t);
    __syncthreads();

    // ---- GEMM1: out1 = wfc . ao ; prefetch w1 half 0 ----
    stage_load(w1_b, r, t);
    {
        f32x4 acc[4] = {};
        #pragma unroll
        for (int kk = 0; kk < 4; ++kk) {
            #pragma unroll
            for (int f = 0; f < 4; ++f) {
                int row = mh * 64 + f * 16 + row16;
                short8v a = *(const short8v*)&wbuf[(row << 7) + (((kk * 4 + g) ^ (row & 7)) << 3)];
                acc[f] = __builtin_amdgcn_mfma_f32_16x16x32_bf16(a, bf[kk], acc[f], 0, 0, 0);
            }
        }
        #pragma unroll
        for (int f = 0; f < 4; ++f)
            #pragma unroll
            for (int e = 0; e < 4; ++e) {
                int o = mh * 64 + f * 16 + g * 4 + e;
                l1[ploc * 128 + (o ^ swz)] = f2bf(acc[f][e]);
            }
    }
    __syncthreads();
    stage_write<4>(r, wbuf, t);
    __syncthreads();

    // ---- GEMM2 halves: hid = leaky(w1 . out1 + b1) ----
    #pragma unroll
    for (int s = 0; s < 2; ++s) {
        if (s == 0) stage_load(w1_b + 16384, r, t);   // prefetch w1 half 1
        else        stage_load(w2_b, r, t);           // prefetch w2 half 0
        f32x4 acc[4] = {};
        #pragma unroll
        for (int kk = 0; kk < 4; ++kk) {
            short8v b = *(const short8v*)&l1[ploc * 128 + ((kk * 32 + g * 8) ^ swz)];
            #pragma unroll
            for (int f = 0; f < 4; ++f) {
                int row = mh * 64 + f * 16 + row16;
                short8v a = *(const short8v*)&wbuf[(row << 7) + (((kk * 4 + g) ^ (row & 7)) << 3)];
                acc[f] = __builtin_amdgcn_mfma_f32_16x16x32_bf16(a, b, acc[f], 0, 0, 0);
            }
        }
        #pragma unroll
        for (int f = 0; f < 4; ++f) {
            int h = s * 128 + mh * 64 + f * 16 + g * 4;
            float4 bb = *(const float4*)&b1[h];
            float hv[4] = {acc[f][0] + bb.x, acc[f][1] + bb.y,
                           acc[f][2] + bb.z, acc[f][3] + bb.w};
            #pragma unroll
            for (int e = 0; e < 4; ++e) {
                float v = (hv[e] >= 0.f) ? hv[e] : 0.2f * hv[e];
                lh[ploc * 256 + ((h + e) ^ swz)] = f2bf(v);
            }
        }
        __syncthreads();
        if (s == 0) stage_write<4>(r, wbuf, t);
        else        stage_write<5>(r, wbuf, t);
        __syncthreads();
    }

    // ---- GEMM3 halves: out2 = w2 . hid + b2 + out1 ----
    float lsum = 0.f, lsq = 0.f;
    #pragma unroll
    for (int s = 0; s < 2; ++s) {
        if (s == 0) stage_load(w2_b + 16384, r, t);   // prefetch w2 half 1
        f32x4 acc[2] = {};
        #pragma unroll
        for (int kk = 0; kk < 8; ++kk) {
            short8v b = *(const short8v*)&lh[ploc * 256 + ((kk * 32 + g * 8) ^ swz)];
            #pragma unroll
            for (int f = 0; f < 2; ++f) {
                int row = mh * 32 + f * 16 + row16;       // local row in [0,64)
                short8v a = *(const short8v*)&wbuf[(row << 8) + (((kk * 4 + g) ^ (row & 7)) << 3)];
                acc[f] = __builtin_amdgcn_mfma_f32_16x16x32_bf16(a, b, acc[f], 0, 0, 0);
            }
        }
        #pragma unroll
        for (int f = 0; f < 2; ++f) {
            int ob = s * 64 + mh * 32 + f * 16 + g * 4;
            float4 b2v = *(const float4*)&b2[ob];
            ushort4 res = *(const ushort4*)&l1[ploc * 128 + (ob ^ swz)];
            float bv[4] = {b2v.x, b2v.y, b2v.z, b2v.w};
            unsigned short rr[4] = {res.x, res.y, res.z, res.w};
            #pragma unroll
            for (int e = 0; e < 4; ++e) {
                float v = acc[f][e] + bf2f(rr[e]) + bv[e];
                out2[(size_t)(ob + e) * HW + pix] = v;
                lsum += v;
                lsq += v * v;
            }
        }
        if (s == 0) {
            __syncthreads();
            stage_write<5>(r, wbuf, t);
            __syncthreads();
        }
    }

    // ---- per-block stats partial (no atomics) ----
    #pragma unroll
    for (int s = 1; s < 64; s <<= 1) {
        lsum += __shfl_xor(lsum, s);
        lsq  += __shfl_xor(lsq, s);
    }
    if (lane == 0) { rs[w] = lsum; rs[4 + w] = lsq; }
    __syncthreads();
    if (t == 0)
        partials[blockIdx.x] = make_float2(rs[0] + rs[1] + rs[2] + rs[3],
                                           rs[4] + rs[5] + rs[6] + rs[7]);
}

// ---------------- kernel 4: global layernorm (in place), per-block partial reduce ----------------
// 1024 blocks x 256 thr, 8 floats (2 x float4) per thread.
__global__ void norm_kernel(float* __restrict__ out2, const float2* __restrict__ partials,
                            const float* __restrict__ gn_w, const float* __restrict__ gn_b) {
    __shared__ float rs[8];
    __shared__ float stat[2];
    const int t = threadIdx.x;

    // redundant per-block reduction of the 512 partials (4 KB, L2-hot)
    float2 p0 = partials[t];
    float2 p1 = partials[t + 256];
    float a = p0.x + p1.x, bb = p0.y + p1.y;
    #pragma unroll
    for (int s = 1; s < 64; s <<= 1) {
        a  += __shfl_xor(a, s);
        bb += __shfl_xor(bb, s);
    }
    if ((t & 63) == 0) { rs[t >> 6] = a; rs[4 + (t >> 6)] = bb; }
    __syncthreads();
    if (t == 0) {
        const float invN = 1.f / 2097152.f;
        float mean = (rs[0] + rs[1] + rs[2] + rs[3]) * invN;
        float var = (rs[4] + rs[5] + rs[6] + rs[7]) * invN - mean * mean;
        stat[0] = mean;
        stat[1] = rsqrtf(var + 1e-5f);
    }
    __syncthreads();

    const float mean = stat[0], rstd = stat[1];
    const size_t base = ((size_t)blockIdx.x * 256 + t) * 8;
    int o = (int)(base >> 14);    // / HW (8 | HW so one channel per thread-chunk)
    float g = gn_w[o] * rstd;
    float b = gn_b[o];
    float4 v0 = *(const float4*)(out2 + base);
    float4 v1 = *(const float4*)(out2 + base + 4);
    float4 r0, r1;
    r0.x = (v0.x - mean) * g + b;
    r0.y = (v0.y - mean) * g + b;
    r0.z = (v0.z - mean) * g + b;
    r0.w = (v0.w - mean) * g + b;
    r1.x = (v1.x - mean) * g + b;
    r1.y = (v1.y - mean) * g + b;
    r1.z = (v1.z - mean) * g + b;
    r1.w = (v1.w - mean) * g + b;
    *(float4*)(out2 + base) = r0;
    *(float4*)(out2 + base + 4) = r1;
}

extern "C" void kernel_launch(void* const* d_in, const int* in_sizes, int n_in,
                              void* d_out, int out_size, void* d_ws, size_t ws_size,
                              hipStream_t stream) {
    const float* query  = (const float*)d_in[0];
    const float* key    = (const float*)d_in[1];
    const float* value  = (const float*)d_in[2];
    const float* deform = (const float*)d_in[3];
    const float* w_q    = (const float*)d_in[4];
    const float* w_k    = (const float*)d_in[5];
    const float* w_v    = (const float*)d_in[6];
    const float* w_fc   = (const float*)d_in[7];
    const float* mlp_w1 = (const float*)d_in[8];
    const float* mlp_b1 = (const float*)d_in[9];
    const float* mlp_w2 = (const float*)d_in[10];
    const float* mlp_b2 = (const float*)d_in[11];
    const float* gn_w   = (const float*)d_in[12];
    const float* gn_b   = (const float*)d_in[13];

    float* out = (float*)d_out;
    char* wsb  = (char*)d_ws;

    // ws layout (bytes): q_t bf16 [0,4M) | kv_t bf16 [4M,12M) | ao bf16 [12M,16M)
    //                    | wb bf16 [16M,+192K) | partials [17M, +4K)
    unsigned short* q_t  = (unsigned short*)wsb;
    unsigned short* kv_t = (unsigned short*)(wsb + ((size_t)4 << 20));
    unsigned short* ao_t = (unsigned short*)(wsb + ((size_t)12 << 20));
    unsigned short* wb   = (unsigned short*)(wsb + ((size_t)16 << 20));
    float2* partials = (float2*)(wsb + ((size_t)17 << 20));

    qkv_mfma<<<512, 256, 0, stream>>>(query, key, value, w_q, w_k, w_v,
                                      w_fc, mlp_w1, mlp_w2, wb, q_t, kv_t);
    attn_kernel<<<1024, 256, 0, stream>>>(q_t, kv_t, deform, ao_t);
    mlp_mfma<<<512, 256, 0, stream>>>(ao_t, wb, mlp_b1, mlp_b2, out, partials);
    norm_kernel<<<1024, 256, 0, stream>>>(out, partials, gn_w, gn_b);
}

// Round 14
// 53.894 us; speedup vs baseline: 1.0098x; 1.0098x over previous
//
#include <hip/hip_runtime.h>
#include <hip/hip_bf16.h>

#define HW 16384
#define W 128
#define C 128
#define HID 256

typedef __attribute__((ext_vector_type(8))) short short8v;
typedef __attribute__((ext_vector_type(4))) float f32x4;

#if defined(__has_builtin)
#if __has_builtin(__builtin_amdgcn_fdot2_f32_bf16)
#define HAVE_FDOT2 1
#endif
#endif
#ifndef HAVE_FDOT2
#define HAVE_FDOT2 0
#endif

#if HAVE_FDOT2
typedef __attribute__((ext_vector_type(2))) __bf16 bf16x2;
#endif

__device__ __forceinline__ unsigned short f2bf(float f) {
    union { float f; unsigned u; } x; x.f = f;
    unsigned r = x.u + 0x7FFF + ((x.u >> 16) & 1);
    return (unsigned short)(r >> 16);
}
__device__ __forceinline__ float bf2f(unsigned short b) {
    union { unsigned u; float f; } x; x.u = ((unsigned)b) << 16;
    return x.f;
}

// ---- async-stage split: issue 32KB panel (8 x 16B per thread) into regs ----
__device__ __forceinline__ void stage_load(const unsigned short* __restrict__ src,
                                           short8v* r, int t) {
    #pragma unroll
    for (int c = 0; c < 8; ++c)
        r[c] = *(const short8v*)(src + (size_t)(c * 256 + t) * 8);
}
// ---- commit regs to LDS, XOR-swizzled: granule col ^= (row&7). RSH=log2(granules/row)
template<int RSH>
__device__ __forceinline__ void stage_write(const short8v* r, unsigned short* lds, int t) {
    #pragma unroll
    for (int c = 0; c < 8; ++c) {
        int gi = c * 256 + t;
        int row = gi >> RSH, colg = gi & ((1 << RSH) - 1);
        *(short8v*)(lds + (size_t)(((row << RSH) + (colg ^ (row & 7))) << 3)) = r[c];
    }
}
// ---- stage a 32KB bf16 panel directly from an f32 weight matrix (converting) ----
template<int RSH>
__device__ __forceinline__ void stage32f(const float* __restrict__ src,
                                         unsigned short* lds, int t) {
    #pragma unroll
    for (int c = 0; c < 8; ++c) {
        int gi = c * 256 + t;
        int row = gi >> RSH, colg = gi & ((1 << RSH) - 1);
        float4 a = *(const float4*)(src + (size_t)gi * 8);
        float4 b = *(const float4*)(src + (size_t)gi * 8 + 4);
        short8v v;
        v[0] = (short)f2bf(a.x); v[1] = (short)f2bf(a.y);
        v[2] = (short)f2bf(a.z); v[3] = (short)f2bf(a.w);
        v[4] = (short)f2bf(b.x); v[5] = (short)f2bf(b.y);
        v[6] = (short)f2bf(b.z); v[7] = (short)f2bf(b.w);
        *(short8v*)(lds + (size_t)(((row << RSH) + (colg ^ (row & 7))) << 3)) = v;
    }
}

// ---------------- kernel 1: q/k/v 1x1 convs via MFMA; also converts mlp weights ----------------
// 512 blocks x 256 thr; 32 px/block. Weight panels staged+converted from f32.
// Input staging: round-12 scalar pattern (float4 variant had 8-way LDS write conflicts).
__global__ __launch_bounds__(256, 2)
void qkv_mfma(const float* __restrict__ q_in, const float* __restrict__ k_in,
              const float* __restrict__ v_in,
              const float* __restrict__ w_q, const float* __restrict__ w_k,
              const float* __restrict__ w_v,
              const float* __restrict__ wfc, const float* __restrict__ w1,
              const float* __restrict__ w2,
              unsigned short* __restrict__ wb,
              unsigned short* __restrict__ q_t, unsigned short* __restrict__ kv_t) {
    __shared__ unsigned short lx[3][32 * 128];   // 24 KB inputs (pixel-swizzled)
    __shared__ unsigned short wbuf[16384];       // 32 KB weight panel
    const int t = threadIdx.x;
    const int p0 = blockIdx.x * 32;
    const int lane = t & 63, row16 = lane & 15, g = lane >> 4;
    const int w = t >> 6, nh = w & 1, mh = w >> 1;
    const int ploc = nh * 16 + row16;
    const int pix = p0 + ploc;
    const int swz = (ploc & 7) << 3;

    stage32f<4>(w_q, wbuf, t);    // wq panel, in flight during x-tile conversion

    // side job: convert mlp weights (98304 f32) spread across 512 blocks
    if (t < 192) {
        int i = blockIdx.x * 192 + t;
        float v = (i < 16384) ? wfc[i] : (i < 49152) ? w1[i - 16384] : w2[i - 49152];
        wb[i] = f2bf(v);
    }

    const float* ins[3] = {q_in, k_in, v_in};
    #pragma unroll
    for (int m = 0; m < 3; ++m) {
        #pragma unroll
        for (int it = 0; it < 16; ++it) {
            int e = t + 256 * it;          // 0..4095
            int p = e & 31, c = e >> 5;
            lx[m][p * 128 + (c ^ ((p & 7) << 3))] = f2bf(ins[m][c * HW + p0 + p]);
        }
    }

    const float* ws[3] = {w_q, w_k, w_v};
    #pragma unroll 1
    for (int m = 0; m < 3; ++m) {
        if (m > 0) {
            __syncthreads();               // previous GEMM done reading wbuf
            stage32f<4>(ws[m], wbuf, t);
        }
        __syncthreads();                   // staging (and lx on m=0) visible

        f32x4 acc[4] = {};
        #pragma unroll
        for (int kk = 0; kk < 4; ++kk) {
            short8v b = *(const short8v*)&lx[m][ploc * 128 + ((kk * 32 + g * 8) ^ swz)];
            #pragma unroll
            for (int f = 0; f < 4; ++f) {
                int row = mh * 64 + f * 16 + row16;
                short8v a = *(const short8v*)&wbuf[(row << 7) + (((kk * 4 + g) ^ (row & 7)) << 3)];
                acc[f] = __builtin_amdgcn_mfma_f32_16x16x32_bf16(a, b, acc[f], 0, 0, 0);
            }
        }
        #pragma unroll
        for (int f = 0; f < 4; ++f) {
            int o = mh * 64 + f * 16 + g * 4;
            ushort4 st;
            st.x = f2bf(acc[f][0]); st.y = f2bf(acc[f][1]);
            st.z = f2bf(acc[f][2]); st.w = f2bf(acc[f][3]);
            if (m == 0)      *(ushort4*)&q_t[(size_t)pix * 128 + o] = st;
            else if (m == 1) *(ushort4*)&kv_t[(size_t)pix * 256 + o] = st;
            else             *(ushort4*)&kv_t[(size_t)pix * 256 + 128 + o] = st;
        }
    }
}

// ---------------- kernel 2: deformable attention, factorized 6x6 corner grid ----------------
// bf16 q/kv, 16B gathers: 16 thr/px, 8 ch/thr, 16 px/block. 1024 blocks.
// Phase A uses v_dot2_f32_bf16 when available (4 insts per 8-ch partial dot).
__global__ __launch_bounds__(256, 2)
void attn_kernel(const unsigned short* __restrict__ q_t, const unsigned short* __restrict__ kv_t,
                 const float* __restrict__ deform, unsigned short* __restrict__ ao_t) {
    const int t = threadIdx.x;
    const int pi = t >> 4;     // pixel within block (16)
    const int g = t & 15;      // channel group (8 ch = 16 B)
    const char* kvb = (const char*)kv_t;
    const int go = g * 16;

    const int jj = blockIdx.x;
    const int y = jj >> 3;
    const int x = ((jj & 7) << 4) + pi;
    const int pix = y * W + x;

    const float dx = deform[pix];
    const float dy = deform[HW + pix];
    const float fdx = floorf(dx), fdy = floorf(dy);
    const float fx = dx - fdx, fy = dy - fdy;
    const float wx0 = 1.f - fx, wx1 = fx, wy0 = 1.f - fy, wy1 = fy;
    const int x0 = x - 2 + (int)fdx;
    const int y0 = y - 2 + (int)fdy;

    int   coff[6], roff[6];
    float colv[6], rowv[6];
    #pragma unroll
    for (int j = 0; j < 6; ++j) {
        int xc = x0 + j, yc = y0 + j;
        colv[j] = ((unsigned)xc <= 127u) ? 1.f : 0.f;
        rowv[j] = ((unsigned)yc <= 127u) ? 1.f : 0.f;
        coff[j] = (min(max(xc, 0), 127) << 9) + go;   // x*512B + channel byte off
        roff[j] = min(max(yc, 0), 127) << 16;         // y*64KB
    }

#if HAVE_FDOT2
    union QU { unsigned short u[8]; bf16x2 b[4]; } qu;
    {
        short8v qv = *(const short8v*)(q_t + (size_t)pix * C + g * 8);
        #pragma unroll
        for (int e = 0; e < 8; ++e)
            qu.u[e] = f2bf(bf2f((unsigned short)qv[e]) * 0.25f);   // *0.25 exact in bf16
    }
#else
    float q[8];
    {
        short8v qv = *(const short8v*)(q_t + (size_t)pix * C + g * 8);
        #pragma unroll
        for (int e = 0; e < 8; ++e) q[e] = bf2f((unsigned short)qv[e]) * 0.25f;
    }
#endif

    // ---- phase A: 36 per-thread partial dots (16B k loads) ----
    float d[36];
    #pragma unroll
    for (int jy = 0; jy < 6; ++jy) {
        #pragma unroll
        for (int jx = 0; jx < 6; ++jx) {
            short8v k = *(const short8v*)(kvb + (roff[jy] + coff[jx]));
#if HAVE_FDOT2
            union KU { short8v s; bf16x2 b[4]; } ku;
            ku.s = k;
            float dd = 0.f;
            dd = __builtin_amdgcn_fdot2_f32_bf16(ku.b[0], qu.b[0], dd, false);
            dd = __builtin_amdgcn_fdot2_f32_bf16(ku.b[1], qu.b[1], dd, false);
            dd = __builtin_amdgcn_fdot2_f32_bf16(ku.b[2], qu.b[2], dd, false);
            dd = __builtin_amdgcn_fdot2_f32_bf16(ku.b[3], qu.b[3], dd, false);
#else
            float dd = 0.f;
            #pragma unroll
            for (int e = 0; e < 8; ++e) dd += q[e] * bf2f((unsigned short)k[e]);
#endif
            d[jy * 6 + jx] = dd * (rowv[jy] * colv[jx]);
        }
    }

    // ---- scores: bilinear combine + head reduce (2 lanes/head) ----
    float s[25];
    #pragma unroll
    for (int iy = 0; iy < 5; ++iy) {
        #pragma unroll
        for (int ix = 0; ix < 5; ++ix) {
            float sp = wy0 * (wx0 * d[iy * 6 + ix]       + wx1 * d[iy * 6 + ix + 1])
                     + wy1 * (wx0 * d[(iy + 1) * 6 + ix] + wx1 * d[(iy + 1) * 6 + ix + 1]);
            sp += __shfl_xor(sp, 1);     // 2 threads = one 16-ch head
            s[iy * 5 + ix] = sp;
        }
    }

    // ---- softmax over 25 (in registers) ----
    float m = s[0];
    #pragma unroll
    for (int p = 1; p < 25; ++p) m = fmaxf(m, s[p]);
    float sum = 0.f;
    #pragma unroll
    for (int p = 0; p < 25; ++p) {
        float e = __expf(s[p] - m);
        s[p] = e;
        sum += e;
    }
    const float inv = 1.f / sum;

    // ---- corner weights: transpose bilinear of probs, fold validity ----
    float b[36];
    #pragma unroll
    for (int jy = 0; jy < 6; ++jy) {
        #pragma unroll
        for (int jx = 0; jx < 6; ++jx) {
            float acc = 0.f;
            if (jy < 5  && jx < 5)  acc += wy0 * wx0 * s[jy * 5 + jx];
            if (jy < 5  && jx >= 1) acc += wy0 * wx1 * s[jy * 5 + jx - 1];
            if (jy >= 1 && jx < 5)  acc += wy1 * wx0 * s[(jy - 1) * 5 + jx];
            if (jy >= 1 && jx >= 1) acc += wy1 * wx1 * s[(jy - 1) * 5 + jx - 1];
            b[jy * 6 + jx] = acc * (rowv[jy] * colv[jx]);
        }
    }

    // ---- phase B: 36 V gathers (16B) ----
    float oc[8] = {0.f, 0.f, 0.f, 0.f, 0.f, 0.f, 0.f, 0.f};
    #pragma unroll
    for (int jy = 0; jy < 6; ++jy) {
        #pragma unroll
        for (int jx = 0; jx < 6; ++jx) {
            short8v v = *(const short8v*)(kvb + (roff[jy] + coff[jx]) + 256);
            float bw = b[jy * 6 + jx];
            #pragma unroll
            for (int e = 0; e < 8; ++e) oc[e] += bw * bf2f((unsigned short)v[e]);
        }
    }

    short8v ob;
    #pragma unroll
    for (int e = 0; e < 8; ++e) ob[e] = (short)f2bf(oc[e] * inv);
    *(short8v*)(ao_t + (size_t)pix * C + g * 8) = ob;
}

// ---------------- kernel 3: fc + MLP + residual + stats via MFMA ----------------
// 512 blocks x 256 thr, 32 px/block; 56KB LDS -> 2 blocks/CU so one block's
// staging hides under the other's MFMA. Pipelined weight staging as before.
__global__ __launch_bounds__(256, 2)
void mlp_mfma(const unsigned short* __restrict__ ao_t, const unsigned short* __restrict__ wb,
              const float* __restrict__ b1, const float* __restrict__ b2,
              float* __restrict__ out2, float2* __restrict__ partials) {
    __shared__ unsigned short wbuf[16384];    // 32 KB weight panel
    __shared__ unsigned short l1[32 * 128];   // out1 bf16 (pixel-swizzled)   8 KB
    __shared__ unsigned short lh[32 * 256];   // hid  bf16 (pixel-swizzled)  16 KB
    __shared__ float rs[8];
    const int t = threadIdx.x;
    const int p0 = blockIdx.x * 32;
    const int lane = t & 63, row16 = lane & 15, g = lane >> 4;
    const int w = t >> 6, nh = w & 1, mh = w >> 1;
    const int ploc = nh * 16 + row16;
    const int pix = p0 + ploc;
    const int swz = (ploc & 7) << 3;
    const unsigned short* wfc_b = wb;
    const unsigned short* w1_b  = wb + 16384;
    const unsigned short* w2_b  = wb + 49152;

    short8v r[8];
    stage_load(wfc_b, r, t);
    // B-fragments for GEMM1 issued early too
    short8v bf[4];
    #pragma unroll
    for (int kk = 0; kk < 4; ++kk)
        bf[kk] = *(const short8v*)&ao_t[(size_t)pix * 128 + kk * 32 + g * 8];
    stage_write<4>(r, wbuf, t);
    __syncthreads();

    // ---- GEMM1: out1 = wfc . ao ; prefetch w1 half 0 ----
    stage_load(w1_b, r, t);
    {
        f32x4 acc[4] = {};
        #pragma unroll
        for (int kk = 0; kk < 4; ++kk) {
            #pragma unroll
            for (int f = 0; f < 4; ++f) {
                int row = mh * 64 + f * 16 + row16;
                short8v a = *(const short8v*)&wbuf[(row << 7) + (((kk * 4 + g) ^ (row & 7)) << 3)];
                acc[f] = __builtin_amdgcn_mfma_f32_16x16x32_bf16(a, bf[kk], acc[f], 0, 0, 0);
            }
        }
        #pragma unroll
        for (int f = 0; f < 4; ++f)
            #pragma unroll
            for (int e = 0; e < 4; ++e) {
                int o = mh * 64 + f * 16 + g * 4 + e;
                l1[ploc * 128 + (o ^ swz)] = f2bf(acc[f][e]);
            }
    }
    __syncthreads();
    stage_write<4>(r, wbuf, t);
    __syncthreads();

    // ---- GEMM2 halves: hid = leaky(w1 . out1 + b1) ----
    #pragma unroll
    for (int s = 0; s < 2; ++s) {
        if (s == 0) stage_load(w1_b + 16384, r, t);   // prefetch w1 half 1
        else        stage_load(w2_b, r, t);           // prefetch w2 half 0
        f32x4 acc[4] = {};
        #pragma unroll
        for (int kk = 0; kk < 4; ++kk) {
            short8v b = *(const short8v*)&l1[ploc * 128 + ((kk * 32 + g * 8) ^ swz)];
            #pragma unroll
            for (int f = 0; f < 4; ++f) {
                int row = mh * 64 + f * 16 + row16;
                short8v a = *(const short8v*)&wbuf[(row << 7) + (((kk * 4 + g) ^ (row & 7)) << 3)];
                acc[f] = __builtin_amdgcn_mfma_f32_16x16x32_bf16(a, b, acc[f], 0, 0, 0);
            }
        }
        #pragma unroll
        for (int f = 0; f < 4; ++f) {
            int h = s * 128 + mh * 64 + f * 16 + g * 4;
            float4 bb = *(const float4*)&b1[h];
            float hv[4] = {acc[f][0] + bb.x, acc[f][1] + bb.y,
                           acc[f][2] + bb.z, acc[f][3] + bb.w};
            #pragma unroll
            for (int e = 0; e < 4; ++e) {
                float v = (hv[e] >= 0.f) ? hv[e] : 0.2f * hv[e];
                lh[ploc * 256 + ((h + e) ^ swz)] = f2bf(v);
            }
        }
        __syncthreads();
        if (s == 0) stage_write<4>(r, wbuf, t);
        else        stage_write<5>(r, wbuf, t);
        __syncthreads();
    }

    // ---- GEMM3 halves: out2 = w2 . hid + b2 + out1 ----
    float lsum = 0.f, lsq = 0.f;
    #pragma unroll
    for (int s = 0; s < 2; ++s) {
        if (s == 0) stage_load(w2_b + 16384, r, t);   // prefetch w2 half 1
        f32x4 acc[2] = {};
        #pragma unroll
        for (int kk = 0; kk < 8; ++kk) {
            short8v b = *(const short8v*)&lh[ploc * 256 + ((kk * 32 + g * 8) ^ swz)];
            #pragma unroll
            for (int f = 0; f < 2; ++f) {
                int row = mh * 32 + f * 16 + row16;       // local row in [0,64)
                short8v a = *(const short8v*)&wbuf[(row << 8) + (((kk * 4 + g) ^ (row & 7)) << 3)];
                acc[f] = __builtin_amdgcn_mfma_f32_16x16x32_bf16(a, b, acc[f], 0, 0, 0);
            }
        }
        #pragma unroll
        for (int f = 0; f < 2; ++f) {
            int ob = s * 64 + mh * 32 + f * 16 + g * 4;
            float4 b2v = *(const float4*)&b2[ob];
            ushort4 res = *(const ushort4*)&l1[ploc * 128 + (ob ^ swz)];
            float bv[4] = {b2v.x, b2v.y, b2v.z, b2v.w};
            unsigned short rr[4] = {res.x, res.y, res.z, res.w};
            #pragma unroll
            for (int e = 0; e < 4; ++e) {
                float v = acc[f][e] + bf2f(rr[e]) + bv[e];
                out2[(size_t)(ob + e) * HW + pix] = v;
                lsum += v;
                lsq += v * v;
            }
        }
        if (s == 0) {
            __syncthreads();
            stage_write<5>(r, wbuf, t);
            __syncthreads();
        }
    }

    // ---- per-block stats partial (no atomics) ----
    #pragma unroll
    for (int s = 1; s < 64; s <<= 1) {
        lsum += __shfl_xor(lsum, s);
        lsq  += __shfl_xor(lsq, s);
    }
    if (lane == 0) { rs[w] = lsum; rs[4 + w] = lsq; }
    __syncthreads();
    if (t == 0)
        partials[blockIdx.x] = make_float2(rs[0] + rs[1] + rs[2] + rs[3],
                                           rs[4] + rs[5] + rs[6] + rs[7]);
}

// ---------------- kernel 4: global layernorm (in place), per-block partial reduce ----------------
// 1024 blocks x 256 thr, 8 floats (2 x float4) per thread.
__global__ void norm_kernel(float* __restrict__ out2, const float2* __restrict__ partials,
                            const float* __restrict__ gn_w, const float* __restrict__ gn_b) {
    __shared__ float rs[8];
    __shared__ float stat[2];
    const int t = threadIdx.x;

    // redundant per-block reduction of the 512 partials (4 KB, L2-hot)
    float2 p0 = partials[t];
    float2 p1 = partials[t + 256];
    float a = p0.x + p1.x, bb = p0.y + p1.y;
    #pragma unroll
    for (int s = 1; s < 64; s <<= 1) {
        a  += __shfl_xor(a, s);
        bb += __shfl_xor(bb, s);
    }
    if ((t & 63) == 0) { rs[t >> 6] = a; rs[4 + (t >> 6)] = bb; }
    __syncthreads();
    if (t == 0) {
        const float invN = 1.f / 2097152.f;
        float mean = (rs[0] + rs[1] + rs[2] + rs[3]) * invN;
        float var = (rs[4] + rs[5] + rs[6] + rs[7]) * invN - mean * mean;
        stat[0] = mean;
        stat[1] = rsqrtf(var + 1e-5f);
    }
    __syncthreads();

    const float mean = stat[0], rstd = stat[1];
    const size_t base = ((size_t)blockIdx.x * 256 + t) * 8;
    int o = (int)(base >> 14);    // / HW (8 | HW so one channel per thread-chunk)
    float g = gn_w[o] * rstd;
    float b = gn_b[o];
    float4 v0 = *(const float4*)(out2 + base);
    float4 v1 = *(const float4*)(out2 + base + 4);
    float4 r0, r1;
    r0.x = (v0.x - mean) * g + b;
    r0.y = (v0.y - mean) * g + b;
    r0.z = (v0.z - mean) * g + b;
    r0.w = (v0.w - mean) * g + b;
    r1.x = (v1.x - mean) * g + b;
    r1.y = (v1.y - mean) * g + b;
    r1.z = (v1.z - mean) * g + b;
    r1.w = (v1.w - mean) * g + b;
    *(float4*)(out2 + base) = r0;
    *(float4*)(out2 + base + 4) = r1;
}

extern "C" void kernel_launch(void* const* d_in, const int* in_sizes, int n_in,
                              void* d_out, int out_size, void* d_ws, size_t ws_size,
                              hipStream_t stream) {
    const float* query  = (const float*)d_in[0];
    const float* key    = (const float*)d_in[1];
    const float* value  = (const float*)d_in[2];
    const float* deform = (const float*)d_in[3];
    const float* w_q    = (const float*)d_in[4];
    const float* w_k    = (const float*)d_in[5];
    const float* w_v    = (const float*)d_in[6];
    const float* w_fc   = (const float*)d_in[7];
    const float* mlp_w1 = (const float*)d_in[8];
    const float* mlp_b1 = (const float*)d_in[9];
    const float* mlp_w2 = (const float*)d_in[10];
    const float* mlp_b2 = (const float*)d_in[11];
    const float* gn_w   = (const float*)d_in[12];
    const float* gn_b   = (const float*)d_in[13];

    float* out = (float*)d_out;
    char* wsb  = (char*)d_ws;

    // ws layout (bytes): q_t bf16 [0,4M) | kv_t bf16 [4M,12M) | ao bf16 [12M,16M)
    //                    | wb bf16 [16M,+192K) | partials [17M, +4K)
    unsigned short* q_t  = (unsigned short*)wsb;
    unsigned short* kv_t = (unsigned short*)(wsb + ((size_t)4 << 20));
    unsigned short* ao_t = (unsigned short*)(wsb + ((size_t)12 << 20));
    unsigned short* wb   = (unsigned short*)(wsb + ((size_t)16 << 20));
    float2* partials = (float2*)(wsb + ((size_t)17 << 20));

    qkv_mfma<<<512, 256, 0, stream>>>(query, key, value, w_q, w_k, w_v,
                                      w_fc, mlp_w1, mlp_w2, wb, q_t, kv_t);
    attn_kernel<<<1024, 256, 0, stream>>>(q_t, kv_t, deform, ao_t);
    mlp_mfma<<<512, 256, 0, stream>>>(ao_t, wb, mlp_b1, mlp_b2, out, partials);
    norm_kernel<<<1024, 256, 0, stream>>>(out, partials, gn_w, gn_b);
}

// Round 15
// 50.728 us; speedup vs baseline: 1.0728x; 1.0624x over previous
//
#include <hip/hip_runtime.h>
#include <hip/hip_bf16.h>

#define HW 16384
#define W 128
#define C 128
#define HID 256

typedef __attribute__((ext_vector_type(8))) short short8v;
typedef __attribute__((ext_vector_type(4))) float f32x4;

__device__ __forceinline__ unsigned short f2bf(float f) {
    union { float f; unsigned u; } x; x.f = f;
    unsigned r = x.u + 0x7FFF + ((x.u >> 16) & 1);
    return (unsigned short)(r >> 16);
}
__device__ __forceinline__ float bf2f(unsigned short b) {
    union { unsigned u; float f; } x; x.u = ((unsigned)b) << 16;
    return x.f;
}

// ---- async-stage split: issue 32KB panel (8 x 16B per thread) into regs ----
__device__ __forceinline__ void stage_load(const unsigned short* __restrict__ src,
                                           short8v* r, int t) {
    #pragma unroll
    for (int c = 0; c < 8; ++c)
        r[c] = *(const short8v*)(src + (size_t)(c * 256 + t) * 8);
}
// ---- commit regs to LDS, XOR-swizzled: granule col ^= (row&7). RSH=log2(granules/row)
template<int RSH>
__device__ __forceinline__ void stage_write(const short8v* r, unsigned short* lds, int t) {
    #pragma unroll
    for (int c = 0; c < 8; ++c) {
        int gi = c * 256 + t;
        int row = gi >> RSH, colg = gi & ((1 << RSH) - 1);
        *(short8v*)(lds + (size_t)(((row << RSH) + (colg ^ (row & 7))) << 3)) = r[c];
    }
}
// ---- stage a 32KB bf16 panel directly from an f32 weight matrix (converting) ----
template<int RSH>
__device__ __forceinline__ void stage32f(const float* __restrict__ src,
                                         unsigned short* lds, int t) {
    #pragma unroll
    for (int c = 0; c < 8; ++c) {
        int gi = c * 256 + t;
        int row = gi >> RSH, colg = gi & ((1 << RSH) - 1);
        float4 a = *(const float4*)(src + (size_t)gi * 8);
        float4 b = *(const float4*)(src + (size_t)gi * 8 + 4);
        short8v v;
        v[0] = (short)f2bf(a.x); v[1] = (short)f2bf(a.y);
        v[2] = (short)f2bf(a.z); v[3] = (short)f2bf(a.w);
        v[4] = (short)f2bf(b.x); v[5] = (short)f2bf(b.y);
        v[6] = (short)f2bf(b.z); v[7] = (short)f2bf(b.w);
        *(short8v*)(lds + (size_t)(((row << RSH) + (colg ^ (row & 7))) << 3)) = v;
    }
}

// ---------------- kernel 1: q/k/v 1x1 convs via MFMA; also converts mlp weights ----------------
// 512 blocks x 256 thr; 32 px/block. Weight panels staged+converted from f32.
__global__ __launch_bounds__(256, 2)
void qkv_mfma(const float* __restrict__ q_in, const float* __restrict__ k_in,
              const float* __restrict__ v_in,
              const float* __restrict__ w_q, const float* __restrict__ w_k,
              const float* __restrict__ w_v,
              const float* __restrict__ wfc, const float* __restrict__ w1,
              const float* __restrict__ w2,
              unsigned short* __restrict__ wb,
              unsigned short* __restrict__ q_t, unsigned short* __restrict__ kv_t) {
    __shared__ unsigned short lx[3][32 * 128];   // 24 KB inputs (pixel-swizzled)
    __shared__ unsigned short wbuf[16384];       // 32 KB weight panel
    const int t = threadIdx.x;
    const int p0 = blockIdx.x * 32;
    const int lane = t & 63, row16 = lane & 15, g = lane >> 4;
    const int w = t >> 6, nh = w & 1, mh = w >> 1;
    const int ploc = nh * 16 + row16;
    const int pix = p0 + ploc;
    const int swz = (ploc & 7) << 3;

    stage32f<4>(w_q, wbuf, t);    // wq panel, in flight during x-tile conversion

    // side job: convert mlp weights (98304 f32) spread across 512 blocks
    if (t < 192) {
        int i = blockIdx.x * 192 + t;
        float v = (i < 16384) ? wfc[i] : (i < 49152) ? w1[i - 16384] : w2[i - 49152];
        wb[i] = f2bf(v);
    }

    const float* ins[3] = {q_in, k_in, v_in};
    #pragma unroll
    for (int m = 0; m < 3; ++m) {
        #pragma unroll
        for (int it = 0; it < 16; ++it) {
            int e = t + 256 * it;          // 0..4095
            int p = e & 31, c = e >> 5;
            lx[m][p * 128 + (c ^ ((p & 7) << 3))] = f2bf(ins[m][c * HW + p0 + p]);
        }
    }

    const float* ws[3] = {w_q, w_k, w_v};
    #pragma unroll 1
    for (int m = 0; m < 3; ++m) {
        if (m > 0) {
            __syncthreads();               // previous GEMM done reading wbuf
            stage32f<4>(ws[m], wbuf, t);
        }
        __syncthreads();                   // staging (and lx on m=0) visible

        f32x4 acc[4] = {};
        #pragma unroll
        for (int kk = 0; kk < 4; ++kk) {
            short8v b = *(const short8v*)&lx[m][ploc * 128 + ((kk * 32 + g * 8) ^ swz)];
            #pragma unroll
            for (int f = 0; f < 4; ++f) {
                int row = mh * 64 + f * 16 + row16;
                short8v a = *(const short8v*)&wbuf[(row << 7) + (((kk * 4 + g) ^ (row & 7)) << 3)];
                acc[f] = __builtin_amdgcn_mfma_f32_16x16x32_bf16(a, b, acc[f], 0, 0, 0);
            }
        }
        #pragma unroll
        for (int f = 0; f < 4; ++f) {
            int o = mh * 64 + f * 16 + g * 4;
            ushort4 st;
            st.x = f2bf(acc[f][0]); st.y = f2bf(acc[f][1]);
            st.z = f2bf(acc[f][2]); st.w = f2bf(acc[f][3]);
            if (m == 0)      *(ushort4*)&q_t[(size_t)pix * 128 + o] = st;
            else if (m == 1) *(ushort4*)&kv_t[(size_t)pix * 256 + o] = st;
            else             *(ushort4*)&kv_t[(size_t)pix * 256 + 128 + o] = st;
        }
    }
}

// ---------------- kernel 2: deformable attention, factorized 6x6 corner grid ----------------
// bf16 q/kv, 16B gathers: 16 thr/px, 8 ch/thr, 16 px/block. 1024 blocks,
// linear bid->tile (dispatch-order sliding L2 window). Plain cvt+FMA dots
// (fdot2 variant measured ~4us SLOWER in R13/R14 — repack cost dominates).
__global__ __launch_bounds__(256, 2)
void attn_kernel(const unsigned short* __restrict__ q_t, const unsigned short* __restrict__ kv_t,
                 const float* __restrict__ deform, unsigned short* __restrict__ ao_t) {
    const int t = threadIdx.x;
    const int pi = t >> 4;     // pixel within block (16)
    const int g = t & 15;      // channel group (8 ch = 16 B)
    const char* kvb = (const char*)kv_t;
    const int go = g * 16;

    const int jj = blockIdx.x;
    const int y = jj >> 3;
    const int x = ((jj & 7) << 4) + pi;
    const int pix = y * W + x;

    const float dx = deform[pix];
    const float dy = deform[HW + pix];
    const float fdx = floorf(dx), fdy = floorf(dy);
    const float fx = dx - fdx, fy = dy - fdy;
    const float wx0 = 1.f - fx, wx1 = fx, wy0 = 1.f - fy, wy1 = fy;
    const int x0 = x - 2 + (int)fdx;
    const int y0 = y - 2 + (int)fdy;

    int   coff[6], roff[6];
    float colv[6], rowv[6];
    #pragma unroll
    for (int j = 0; j < 6; ++j) {
        int xc = x0 + j, yc = y0 + j;
        colv[j] = ((unsigned)xc <= 127u) ? 1.f : 0.f;
        rowv[j] = ((unsigned)yc <= 127u) ? 1.f : 0.f;
        coff[j] = (min(max(xc, 0), 127) << 9) + go;   // x*512B + channel byte off
        roff[j] = min(max(yc, 0), 127) << 16;         // y*64KB
    }

    float q[8];
    {
        short8v qv = *(const short8v*)(q_t + (size_t)pix * C + g * 8);
        #pragma unroll
        for (int e = 0; e < 8; ++e) q[e] = bf2f((unsigned short)qv[e]) * 0.25f;  // 1/sqrt(16)
    }

    // ---- phase A: 36 per-thread partial dots (16B k loads) ----
    float d[36];
    #pragma unroll
    for (int jy = 0; jy < 6; ++jy) {
        #pragma unroll
        for (int jx = 0; jx < 6; ++jx) {
            short8v k = *(const short8v*)(kvb + (roff[jy] + coff[jx]));
            float dd = 0.f;
            #pragma unroll
            for (int e = 0; e < 8; ++e) dd += q[e] * bf2f((unsigned short)k[e]);
            d[jy * 6 + jx] = dd * (rowv[jy] * colv[jx]);
        }
    }

    // ---- scores: bilinear combine + head reduce (2 lanes/head) ----
    float s[25];
    #pragma unroll
    for (int iy = 0; iy < 5; ++iy) {
        #pragma unroll
        for (int ix = 0; ix < 5; ++ix) {
            float sp = wy0 * (wx0 * d[iy * 6 + ix]       + wx1 * d[iy * 6 + ix + 1])
                     + wy1 * (wx0 * d[(iy + 1) * 6 + ix] + wx1 * d[(iy + 1) * 6 + ix + 1]);
            sp += __shfl_xor(sp, 1);     // 2 threads = one 16-ch head
            s[iy * 5 + ix] = sp;
        }
    }

    // ---- softmax over 25 (in registers) ----
    float m = s[0];
    #pragma unroll
    for (int p = 1; p < 25; ++p) m = fmaxf(m, s[p]);
    float sum = 0.f;
    #pragma unroll
    for (int p = 0; p < 25; ++p) {
        float e = __expf(s[p] - m);
        s[p] = e;
        sum += e;
    }
    const float inv = 1.f / sum;

    // ---- corner weights: transpose bilinear of probs, fold validity ----
    float b[36];
    #pragma unroll
    for (int jy = 0; jy < 6; ++jy) {
        #pragma unroll
        for (int jx = 0; jx < 6; ++jx) {
            float acc = 0.f;
            if (jy < 5  && jx < 5)  acc += wy0 * wx0 * s[jy * 5 + jx];
            if (jy < 5  && jx >= 1) acc += wy0 * wx1 * s[jy * 5 + jx - 1];
            if (jy >= 1 && jx < 5)  acc += wy1 * wx0 * s[(jy - 1) * 5 + jx];
            if (jy >= 1 && jx >= 1) acc += wy1 * wx1 * s[(jy - 1) * 5 + jx - 1];
            b[jy * 6 + jx] = acc * (rowv[jy] * colv[jx]);
        }
    }

    // ---- phase B: 36 V gathers (16B) ----
    float oc[8] = {0.f, 0.f, 0.f, 0.f, 0.f, 0.f, 0.f, 0.f};
    #pragma unroll
    for (int jy = 0; jy < 6; ++jy) {
        #pragma unroll
        for (int jx = 0; jx < 6; ++jx) {
            short8v v = *(const short8v*)(kvb + (roff[jy] + coff[jx]) + 256);
            float bw = b[jy * 6 + jx];
            #pragma unroll
            for (int e = 0; e < 8; ++e) oc[e] += bw * bf2f((unsigned short)v[e]);
        }
    }

    short8v ob;
    #pragma unroll
    for (int e = 0; e < 8; ++e) ob[e] = (short)f2bf(oc[e] * inv);
    *(short8v*)(ao_t + (size_t)pix * C + g * 8) = ob;
}

// ---------------- kernel 3: fc + MLP + residual + stats via MFMA ----------------
// 512 blocks x 256 thr, 32 px/block; 56KB LDS -> 2 blocks/CU so one block's
// staging hides under the other's MFMA. Pipelined weight staging as before.
__global__ __launch_bounds__(256, 2)
void mlp_mfma(const unsigned short* __restrict__ ao_t, const unsigned short* __restrict__ wb,
              const float* __restrict__ b1, const float* __restrict__ b2,
              float* __restrict__ out2, float2* __restrict__ partials) {
    __shared__ unsigned short wbuf[16384];    // 32 KB weight panel
    __shared__ unsigned short l1[32 * 128];   // out1 bf16 (pixel-swizzled)   8 KB
    __shared__ unsigned short lh[32 * 256];   // hid  bf16 (pixel-swizzled)  16 KB
    __shared__ float rs[8];
    const int t = threadIdx.x;
    const int p0 = blockIdx.x * 32;
    const int lane = t & 63, row16 = lane & 15, g = lane >> 4;
    const int w = t >> 6, nh = w & 1, mh = w >> 1;
    const int ploc = nh * 16 + row16;
    const int pix = p0 + ploc;
    const int swz = (ploc & 7) << 3;
    const unsigned short* wfc_b = wb;
    const unsigned short* w1_b  = wb + 16384;
    const unsigned short* w2_b  = wb + 49152;

    short8v r[8];
    stage_load(wfc_b, r, t);
    // B-fragments for GEMM1 issued early too
    short8v bf[4];
    #pragma unroll
    for (int kk = 0; kk < 4; ++kk)
        bf[kk] = *(const short8v*)&ao_t[(size_t)pix * 128 + kk * 32 + g * 8];
    stage_write<4>(r, wbuf, t);
    __syncthreads();

    // ---- GEMM1: out1 = wfc . ao ; prefetch w1 half 0 ----
    stage_load(w1_b, r, t);
    {
        f32x4 acc[4] = {};
        #pragma unroll
        for (int kk = 0; kk < 4; ++kk) {
            #pragma unroll
            for (int f = 0; f < 4; ++f) {
                int row = mh * 64 + f * 16 + row16;
                short8v a = *(const short8v*)&wbuf[(row << 7) + (((kk * 4 + g) ^ (row & 7)) << 3)];
                acc[f] = __builtin_amdgcn_mfma_f32_16x16x32_bf16(a, bf[kk], acc[f], 0, 0, 0);
            }
        }
        #pragma unroll
        for (int f = 0; f < 4; ++f)
            #pragma unroll
            for (int e = 0; e < 4; ++e) {
                int o = mh * 64 + f * 16 + g * 4 + e;
                l1[ploc * 128 + (o ^ swz)] = f2bf(acc[f][e]);
            }
    }
    __syncthreads();
    stage_write<4>(r, wbuf, t);
    __syncthreads();

    // ---- GEMM2 halves: hid = leaky(w1 . out1 + b1) ----
    #pragma unroll
    for (int s = 0; s < 2; ++s) {
        if (s == 0) stage_load(w1_b + 16384, r, t);   // prefetch w1 half 1
        else        stage_load(w2_b, r, t);           // prefetch w2 half 0
        f32x4 acc[4] = {};
        #pragma unroll
        for (int kk = 0; kk < 4; ++kk) {
            short8v b = *(const short8v*)&l1[ploc * 128 + ((kk * 32 + g * 8) ^ swz)];
            #pragma unroll
            for (int f = 0; f < 4; ++f) {
                int row = mh * 64 + f * 16 + row16;
                short8v a = *(const short8v*)&wbuf[(row << 7) + (((kk * 4 + g) ^ (row & 7)) << 3)];
                acc[f] = __builtin_amdgcn_mfma_f32_16x16x32_bf16(a, b, acc[f], 0, 0, 0);
            }
        }
        #pragma unroll
        for (int f = 0; f < 4; ++f) {
            int h = s * 128 + mh * 64 + f * 16 + g * 4;
            float4 bb = *(const float4*)&b1[h];
            float hv[4] = {acc[f][0] + bb.x, acc[f][1] + bb.y,
                           acc[f][2] + bb.z, acc[f][3] + bb.w};
            #pragma unroll
            for (int e = 0; e < 4; ++e) {
                float v = (hv[e] >= 0.f) ? hv[e] : 0.2f * hv[e];
                lh[ploc * 256 + ((h + e) ^ swz)] = f2bf(v);
            }
        }
        __syncthreads();
        if (s == 0) stage_write<4>(r, wbuf, t);
        else        stage_write<5>(r, wbuf, t);
        __syncthreads();
    }

    // ---- GEMM3 halves: out2 = w2 . hid + b2 + out1 ----
    float lsum = 0.f, lsq = 0.f;
    #pragma unroll
    for (int s = 0; s < 2; ++s) {
        if (s == 0) stage_load(w2_b + 16384, r, t);   // prefetch w2 half 1
        f32x4 acc[2] = {};
        #pragma unroll
        for (int kk = 0; kk < 8; ++kk) {
            short8v b = *(const short8v*)&lh[ploc * 256 + ((kk * 32 + g * 8) ^ swz)];
            #pragma unroll
            for (int f = 0; f < 2; ++f) {
                int row = mh * 32 + f * 16 + row16;       // local row in [0,64)
                short8v a = *(const short8v*)&wbuf[(row << 8) + (((kk * 4 + g) ^ (row & 7)) << 3)];
                acc[f] = __builtin_amdgcn_mfma_f32_16x16x32_bf16(a, b, acc[f], 0, 0, 0);
            }
        }
        #pragma unroll
        for (int f = 0; f < 2; ++f) {
            int ob = s * 64 + mh * 32 + f * 16 + g * 4;
            float4 b2v = *(const float4*)&b2[ob];
            ushort4 res = *(const ushort4*)&l1[ploc * 128 + (ob ^ swz)];
            float bv[4] = {b2v.x, b2v.y, b2v.z, b2v.w};
            unsigned short rr[4] = {res.x, res.y, res.z, res.w};
            #pragma unroll
            for (int e = 0; e < 4; ++e) {
                float v = acc[f][e] + bf2f(rr[e]) + bv[e];
                out2[(size_t)(ob + e) * HW + pix] = v;
                lsum += v;
                lsq += v * v;
            }
        }
        if (s == 0) {
            __syncthreads();
            stage_write<5>(r, wbuf, t);
            __syncthreads();
        }
    }

    // ---- per-block stats partial (no atomics) ----
    #pragma unroll
    for (int s = 1; s < 64; s <<= 1) {
        lsum += __shfl_xor(lsum, s);
        lsq  += __shfl_xor(lsq, s);
    }
    if (lane == 0) { rs[w] = lsum; rs[4 + w] = lsq; }
    __syncthreads();
    if (t == 0)
        partials[blockIdx.x] = make_float2(rs[0] + rs[1] + rs[2] + rs[3],
                                           rs[4] + rs[5] + rs[6] + rs[7]);
}

// ---------------- kernel 4: global layernorm (in place), per-block partial reduce ----------------
// 1024 blocks x 256 thr, 8 floats (2 x float4) per thread.
__global__ void norm_kernel(float* __restrict__ out2, const float2* __restrict__ partials,
                            const float* __restrict__ gn_w, const float* __restrict__ gn_b) {
    __shared__ float rs[8];
    __shared__ float stat[2];
    const int t = threadIdx.x;

    // redundant per-block reduction of the 512 partials (4 KB, L2-hot)
    float2 p0 = partials[t];
    float2 p1 = partials[t + 256];
    float a = p0.x + p1.x, bb = p0.y + p1.y;
    #pragma unroll
    for (int s = 1; s < 64; s <<= 1) {
        a  += __shfl_xor(a, s);
        bb += __shfl_xor(bb, s);
    }
    if ((t & 63) == 0) { rs[t >> 6] = a; rs[4 + (t >> 6)] = bb; }
    __syncthreads();
    if (t == 0) {
        const float invN = 1.f / 2097152.f;
        float mean = (rs[0] + rs[1] + rs[2] + rs[3]) * invN;
        float var = (rs[4] + rs[5] + rs[6] + rs[7]) * invN - mean * mean;
        stat[0] = mean;
        stat[1] = rsqrtf(var + 1e-5f);
    }
    __syncthreads();

    const float mean = stat[0], rstd = stat[1];
    const size_t base = ((size_t)blockIdx.x * 256 + t) * 8;
    int o = (int)(base >> 14);    // / HW (8 | HW so one channel per thread-chunk)
    float g = gn_w[o] * rstd;
    float b = gn_b[o];
    float4 v0 = *(const float4*)(out2 + base);
    float4 v1 = *(const float4*)(out2 + base + 4);
    float4 r0, r1;
    r0.x = (v0.x - mean) * g + b;
    r0.y = (v0.y - mean) * g + b;
    r0.z = (v0.z - mean) * g + b;
    r0.w = (v0.w - mean) * g + b;
    r1.x = (v1.x - mean) * g + b;
    r1.y = (v1.y - mean) * g + b;
    r1.z = (v1.z - mean) * g + b;
    r1.w = (v1.w - mean) * g + b;
    *(float4*)(out2 + base) = r0;
    *(float4*)(out2 + base + 4) = r1;
}

extern "C" void kernel_launch(void* const* d_in, const int* in_sizes, int n_in,
                              void* d_out, int out_size, void* d_ws, size_t ws_size,
                              hipStream_t stream) {
    const float* query  = (const float*)d_in[0];
    const float* key    = (const float*)d_in[1];
    const float* value  = (const float*)d_in[2];
    const float* deform = (const float*)d_in[3];
    const float* w_q    = (const float*)d_in[4];
    const float* w_k    = (const float*)d_in[5];
    const float* w_v    = (const float*)d_in[6];
    const float* w_fc   = (const float*)d_in[7];
    const float* mlp_w1 = (const float*)d_in[8];
    const float* mlp_b1 = (const float*)d_in[9];
    const float* mlp_w2 = (const float*)d_in[10];
    const float* mlp_b2 = (const float*)d_in[11];
    const float* gn_w   = (const float*)d_in[12];
    const float* gn_b   = (const float*)d_in[13];

    float* out = (float*)d_out;
    char* wsb  = (char*)d_ws;

    // ws layout (bytes): q_t bf16 [0,4M) | kv_t bf16 [4M,12M) | ao bf16 [12M,16M)
    //                    | wb bf16 [16M,+192K) | partials [17M, +4K)
    unsigned short* q_t  = (unsigned short*)wsb;
    unsigned short* kv_t = (unsigned short*)(wsb + ((size_t)4 << 20));
    unsigned short* ao_t = (unsigned short*)(wsb + ((size_t)12 << 20));
    unsigned short* wb   = (unsigned short*)(wsb + ((size_t)16 << 20));
    float2* partials = (float2*)(wsb + ((size_t)17 << 20));

    qkv_mfma<<<512, 256, 0, stream>>>(query, key, value, w_q, w_k, w_v,
                                      w_fc, mlp_w1, mlp_w2, wb, q_t, kv_t);
    attn_kernel<<<1024, 256, 0, stream>>>(q_t, kv_t, deform, ao_t);
    mlp_mfma<<<512, 256, 0, stream>>>(ao_t, wb, mlp_b1, mlp_b2, out, partials);
    norm_kernel<<<1024, 256, 0, stream>>>(out, partials, gn_w, gn_b);
}

// Round 16
// 50.269 us; speedup vs baseline: 1.0826x; 1.0091x over previous
//
#include <hip/hip_runtime.h>
#include <hip/hip_bf16.h>

#define HW 16384
#define W 128
#define C 128
#define HID 256

typedef __attribute__((ext_vector_type(8))) short short8v;
typedef __attribute__((ext_vector_type(4))) float f32x4;

__device__ __forceinline__ unsigned short f2bf(float f) {
    union { float f; unsigned u; } x; x.f = f;
    unsigned r = x.u + 0x7FFF + ((x.u >> 16) & 1);
    return (unsigned short)(r >> 16);
}
__device__ __forceinline__ float bf2f(unsigned short b) {
    union { unsigned u; float f; } x; x.u = ((unsigned)b) << 16;
    return x.f;
}

// ---- async-stage split: issue 32KB panel (8 x 16B per thread) into regs ----
__device__ __forceinline__ void stage_load(const unsigned short* __restrict__ src,
                                           short8v* r, int t) {
    #pragma unroll
    for (int c = 0; c < 8; ++c)
        r[c] = *(const short8v*)(src + (size_t)(c * 256 + t) * 8);
}
// ---- f32 variant: load 64KB f32 panel, convert to bf16 in regs (32 VGPR) ----
__device__ __forceinline__ void stage_load_fcvt(const float* __restrict__ src,
                                                short8v* r, int t) {
    #pragma unroll
    for (int c = 0; c < 8; ++c) {
        float4 a = *(const float4*)(src + (size_t)(c * 256 + t) * 8);
        float4 b = *(const float4*)(src + (size_t)(c * 256 + t) * 8 + 4);
        short8v v;
        v[0] = (short)f2bf(a.x); v[1] = (short)f2bf(a.y);
        v[2] = (short)f2bf(a.z); v[3] = (short)f2bf(a.w);
        v[4] = (short)f2bf(b.x); v[5] = (short)f2bf(b.y);
        v[6] = (short)f2bf(b.z); v[7] = (short)f2bf(b.w);
        r[c] = v;
    }
}
// ---- commit regs to LDS, XOR-swizzled: granule col ^= (row&7). RSH=log2(granules/row)
template<int RSH>
__device__ __forceinline__ void stage_write(const short8v* r, unsigned short* lds, int t) {
    #pragma unroll
    for (int c = 0; c < 8; ++c) {
        int gi = c * 256 + t;
        int row = gi >> RSH, colg = gi & ((1 << RSH) - 1);
        *(short8v*)(lds + (size_t)(((row << RSH) + (colg ^ (row & 7))) << 3)) = r[c];
    }
}

// ---------------- kernel 1: q/k/v 1x1 convs via MFMA; also converts mlp weights ----------------
// 512 blocks x 256 thr; 32 px/block. Weight panels async-staged: next panel's
// loads (f32->bf16 in regs) issue during the current GEMM, commit after sync.
__global__ __launch_bounds__(256, 2)
void qkv_mfma(const float* __restrict__ q_in, const float* __restrict__ k_in,
              const float* __restrict__ v_in,
              const float* __restrict__ w_q, const float* __restrict__ w_k,
              const float* __restrict__ w_v,
              const float* __restrict__ wfc, const float* __restrict__ w1,
              const float* __restrict__ w2,
              unsigned short* __restrict__ wb,
              unsigned short* __restrict__ q_t, unsigned short* __restrict__ kv_t) {
    __shared__ unsigned short lx[3][32 * 128];   // 24 KB inputs (pixel-swizzled)
    __shared__ unsigned short wbuf[16384];       // 32 KB weight panel
    const int t = threadIdx.x;
    const int p0 = blockIdx.x * 32;
    const int lane = t & 63, row16 = lane & 15, g = lane >> 4;
    const int w = t >> 6, nh = w & 1, mh = w >> 1;
    const int ploc = nh * 16 + row16;
    const int pix = p0 + ploc;
    const int swz = (ploc & 7) << 3;

    short8v rw[8];
    stage_load_fcvt(w_q, rw, t);    // wq panel, in flight during x-tile conversion

    // side job: convert mlp weights (98304 f32) spread across 512 blocks
    if (t < 192) {
        int i = blockIdx.x * 192 + t;
        float v = (i < 16384) ? wfc[i] : (i < 49152) ? w1[i - 16384] : w2[i - 49152];
        wb[i] = f2bf(v);
    }

    const float* ins[3] = {q_in, k_in, v_in};
    #pragma unroll
    for (int m = 0; m < 3; ++m) {
        #pragma unroll
        for (int it = 0; it < 16; ++it) {
            int e = t + 256 * it;          // 0..4095
            int p = e & 31, c = e >> 5;
            lx[m][p * 128 + (c ^ ((p & 7) << 3))] = f2bf(ins[m][c * HW + p0 + p]);
        }
    }
    stage_write<4>(rw, wbuf, t);
    __syncthreads();

    const float* ws[3] = {w_q, w_k, w_v};
    #pragma unroll
    for (int m = 0; m < 3; ++m) {
        if (m < 2) stage_load_fcvt(ws[m + 1], rw, t);   // prefetch next panel

        f32x4 acc[4] = {};
        #pragma unroll
        for (int kk = 0; kk < 4; ++kk) {
            short8v b = *(const short8v*)&lx[m][ploc * 128 + ((kk * 32 + g * 8) ^ swz)];
            #pragma unroll
            for (int f = 0; f < 4; ++f) {
                int row = mh * 64 + f * 16 + row16;
                short8v a = *(const short8v*)&wbuf[(row << 7) + (((kk * 4 + g) ^ (row & 7)) << 3)];
                acc[f] = __builtin_amdgcn_mfma_f32_16x16x32_bf16(a, b, acc[f], 0, 0, 0);
            }
        }
        #pragma unroll
        for (int f = 0; f < 4; ++f) {
            int o = mh * 64 + f * 16 + g * 4;
            ushort4 st;
            st.x = f2bf(acc[f][0]); st.y = f2bf(acc[f][1]);
            st.z = f2bf(acc[f][2]); st.w = f2bf(acc[f][3]);
            if (m == 0)      *(ushort4*)&q_t[(size_t)pix * 128 + o] = st;
            else if (m == 1) *(ushort4*)&kv_t[(size_t)pix * 256 + o] = st;
            else             *(ushort4*)&kv_t[(size_t)pix * 256 + 128 + o] = st;
        }

        if (m < 2) {
            __syncthreads();               // all waves done reading wbuf
            stage_write<4>(rw, wbuf, t);
            __syncthreads();               // new panel visible
        }
    }
}

// ---------------- kernel 2: deformable attention, factorized 6x6 corner grid ----------------
// bf16 q/kv, 16B gathers: 16 thr/px, 8 ch/thr, 16 px/block. 1024 blocks,
// linear bid->tile (dispatch-order sliding L2 window). Plain cvt+FMA dots
// (fdot2 variant measured ~4us SLOWER in R13/R14 — repack cost dominates).
__global__ __launch_bounds__(256, 2)
void attn_kernel(const unsigned short* __restrict__ q_t, const unsigned short* __restrict__ kv_t,
                 const float* __restrict__ deform, unsigned short* __restrict__ ao_t) {
    const int t = threadIdx.x;
    const int pi = t >> 4;     // pixel within block (16)
    const int g = t & 15;      // channel group (8 ch = 16 B)
    const char* kvb = (const char*)kv_t;
    const int go = g * 16;

    const int jj = blockIdx.x;
    const int y = jj >> 3;
    const int x = ((jj & 7) << 4) + pi;
    const int pix = y * W + x;

    const float dx = deform[pix];
    const float dy = deform[HW + pix];
    const float fdx = floorf(dx), fdy = floorf(dy);
    const float fx = dx - fdx, fy = dy - fdy;
    const float wx0 = 1.f - fx, wx1 = fx, wy0 = 1.f - fy, wy1 = fy;
    const int x0 = x - 2 + (int)fdx;
    const int y0 = y - 2 + (int)fdy;

    int   coff[6], roff[6];
    float colv[6], rowv[6];
    #pragma unroll
    for (int j = 0; j < 6; ++j) {
        int xc = x0 + j, yc = y0 + j;
        colv[j] = ((unsigned)xc <= 127u) ? 1.f : 0.f;
        rowv[j] = ((unsigned)yc <= 127u) ? 1.f : 0.f;
        coff[j] = (min(max(xc, 0), 127) << 9) + go;   // x*512B + channel byte off
        roff[j] = min(max(yc, 0), 127) << 16;         // y*64KB
    }

    float q[8];
    {
        short8v qv = *(const short8v*)(q_t + (size_t)pix * C + g * 8);
        #pragma unroll
        for (int e = 0; e < 8; ++e) q[e] = bf2f((unsigned short)qv[e]) * 0.25f;  // 1/sqrt(16)
    }

    // ---- phase A: 36 per-thread partial dots (16B k loads) ----
    float d[36];
    #pragma unroll
    for (int jy = 0; jy < 6; ++jy) {
        #pragma unroll
        for (int jx = 0; jx < 6; ++jx) {
            short8v k = *(const short8v*)(kvb + (roff[jy] + coff[jx]));
            float dd = 0.f;
            #pragma unroll
            for (int e = 0; e < 8; ++e) dd += q[e] * bf2f((unsigned short)k[e]);
            d[jy * 6 + jx] = dd * (rowv[jy] * colv[jx]);
        }
    }

    // ---- scores: bilinear combine + head reduce (2 lanes/head) ----
    float s[25];
    #pragma unroll
    for (int iy = 0; iy < 5; ++iy) {
        #pragma unroll
        for (int ix = 0; ix < 5; ++ix) {
            float sp = wy0 * (wx0 * d[iy * 6 + ix]       + wx1 * d[iy * 6 + ix + 1])
                     + wy1 * (wx0 * d[(iy + 1) * 6 + ix] + wx1 * d[(iy + 1) * 6 + ix + 1]);
            sp += __shfl_xor(sp, 1);     // 2 threads = one 16-ch head
            s[iy * 5 + ix] = sp;
        }
    }

    // ---- softmax over 25 (in registers) ----
    float m = s[0];
    #pragma unroll
    for (int p = 1; p < 25; ++p) m = fmaxf(m, s[p]);
    float sum = 0.f;
    #pragma unroll
    for (int p = 0; p < 25; ++p) {
        float e = __expf(s[p] - m);
        s[p] = e;
        sum += e;
    }
    const float inv = 1.f / sum;

    // ---- corner weights: transpose bilinear of probs, fold validity ----
    float b[36];
    #pragma unroll
    for (int jy = 0; jy < 6; ++jy) {
        #pragma unroll
        for (int jx = 0; jx < 6; ++jx) {
            float acc = 0.f;
            if (jy < 5  && jx < 5)  acc += wy0 * wx0 * s[jy * 5 + jx];
            if (jy < 5  && jx >= 1) acc += wy0 * wx1 * s[jy * 5 + jx - 1];
            if (jy >= 1 && jx < 5)  acc += wy1 * wx0 * s[(jy - 1) * 5 + jx];
            if (jy >= 1 && jx >= 1) acc += wy1 * wx1 * s[(jy - 1) * 5 + jx - 1];
            b[jy * 6 + jx] = acc * (rowv[jy] * colv[jx]);
        }
    }

    // ---- phase B: 36 V gathers (16B) ----
    float oc[8] = {0.f, 0.f, 0.f, 0.f, 0.f, 0.f, 0.f, 0.f};
    #pragma unroll
    for (int jy = 0; jy < 6; ++jy) {
        #pragma unroll
        for (int jx = 0; jx < 6; ++jx) {
            short8v v = *(const short8v*)(kvb + (roff[jy] + coff[jx]) + 256);
            float bw = b[jy * 6 + jx];
            #pragma unroll
            for (int e = 0; e < 8; ++e) oc[e] += bw * bf2f((unsigned short)v[e]);
        }
    }

    short8v ob;
    #pragma unroll
    for (int e = 0; e < 8; ++e) ob[e] = (short)f2bf(oc[e] * inv);
    *(short8v*)(ao_t + (size_t)pix * C + g * 8) = ob;
}

// ---------------- kernel 3: fc + MLP + residual + stats via MFMA ----------------
// 512 blocks x 256 thr, 32 px/block; 56KB LDS -> 2 blocks/CU so one block's
// staging hides under the other's MFMA. Pipelined weight staging as before.
__global__ __launch_bounds__(256, 2)
void mlp_mfma(const unsigned short* __restrict__ ao_t, const unsigned short* __restrict__ wb,
              const float* __restrict__ b1, const float* __restrict__ b2,
              float* __restrict__ out2, float2* __restrict__ partials) {
    __shared__ unsigned short wbuf[16384];    // 32 KB weight panel
    __shared__ unsigned short l1[32 * 128];   // out1 bf16 (pixel-swizzled)   8 KB
    __shared__ unsigned short lh[32 * 256];   // hid  bf16 (pixel-swizzled)  16 KB
    __shared__ float rs[8];
    const int t = threadIdx.x;
    const int p0 = blockIdx.x * 32;
    const int lane = t & 63, row16 = lane & 15, g = lane >> 4;
    const int w = t >> 6, nh = w & 1, mh = w >> 1;
    const int ploc = nh * 16 + row16;
    const int pix = p0 + ploc;
    const int swz = (ploc & 7) << 3;
    const unsigned short* wfc_b = wb;
    const unsigned short* w1_b  = wb + 16384;
    const unsigned short* w2_b  = wb + 49152;

    short8v r[8];
    stage_load(wfc_b, r, t);
    // B-fragments for GEMM1 issued early too
    short8v bf[4];
    #pragma unroll
    for (int kk = 0; kk < 4; ++kk)
        bf[kk] = *(const short8v*)&ao_t[(size_t)pix * 128 + kk * 32 + g * 8];
    stage_write<4>(r, wbuf, t);
    __syncthreads();

    // ---- GEMM1: out1 = wfc . ao ; prefetch w1 half 0 ----
    stage_load(w1_b, r, t);
    {
        f32x4 acc[4] = {};
        #pragma unroll
        for (int kk = 0; kk < 4; ++kk) {
            #pragma unroll
            for (int f = 0; f < 4; ++f) {
                int row = mh * 64 + f * 16 + row16;
                short8v a = *(const short8v*)&wbuf[(row << 7) + (((kk * 4 + g) ^ (row & 7)) << 3)];
                acc[f] = __builtin_amdgcn_mfma_f32_16x16x32_bf16(a, bf[kk], acc[f], 0, 0, 0);
            }
        }
        #pragma unroll
        for (int f = 0; f < 4; ++f)
            #pragma unroll
            for (int e = 0; e < 4; ++e) {
                int o = mh * 64 + f * 16 + g * 4 + e;
                l1[ploc * 128 + (o ^ swz)] = f2bf(acc[f][e]);
            }
    }
    __syncthreads();
    stage_write<4>(r, wbuf, t);
    __syncthreads();

    // ---- GEMM2 halves: hid = leaky(w1 . out1 + b1) ----
    #pragma unroll
    for (int s = 0; s < 2; ++s) {
        if (s == 0) stage_load(w1_b + 16384, r, t);   // prefetch w1 half 1
        else        stage_load(w2_b, r, t);           // prefetch w2 half 0
        f32x4 acc[4] = {};
        #pragma unroll
        for (int kk = 0; kk < 4; ++kk) {
            short8v b = *(const short8v*)&l1[ploc * 128 + ((kk * 32 + g * 8) ^ swz)];
            #pragma unroll
            for (int f = 0; f < 4; ++f) {
                int row = mh * 64 + f * 16 + row16;
                short8v a = *(const short8v*)&wbuf[(row << 7) + (((kk * 4 + g) ^ (row & 7)) << 3)];
                acc[f] = __builtin_amdgcn_mfma_f32_16x16x32_bf16(a, b, acc[f], 0, 0, 0);
            }
        }
        #pragma unroll
        for (int f = 0; f < 4; ++f) {
            int h = s * 128 + mh * 64 + f * 16 + g * 4;
            float4 bb = *(const float4*)&b1[h];
            float hv[4] = {acc[f][0] + bb.x, acc[f][1] + bb.y,
                           acc[f][2] + bb.z, acc[f][3] + bb.w};
            #pragma unroll
            for (int e = 0; e < 4; ++e) {
                float v = (hv[e] >= 0.f) ? hv[e] : 0.2f * hv[e];
                lh[ploc * 256 + ((h + e) ^ swz)] = f2bf(v);
            }
        }
        __syncthreads();
        if (s == 0) stage_write<4>(r, wbuf, t);
        else        stage_write<5>(r, wbuf, t);
        __syncthreads();
    }

    // ---- GEMM3 halves: out2 = w2 . hid + b2 + out1 ----
    float lsum = 0.f, lsq = 0.f;
    #pragma unroll
    for (int s = 0; s < 2; ++s) {
        if (s == 0) stage_load(w2_b + 16384, r, t);   // prefetch w2 half 1
        f32x4 acc[2] = {};
        #pragma unroll
        for (int kk = 0; kk < 8; ++kk) {
            short8v b = *(const short8v*)&lh[ploc * 256 + ((kk * 32 + g * 8) ^ swz)];
            #pragma unroll
            for (int f = 0; f < 2; ++f) {
                int row = mh * 32 + f * 16 + row16;       // local row in [0,64)
                short8v a = *(const short8v*)&wbuf[(row << 8) + (((kk * 4 + g) ^ (row & 7)) << 3)];
                acc[f] = __builtin_amdgcn_mfma_f32_16x16x32_bf16(a, b, acc[f], 0, 0, 0);
            }
        }
        #pragma unroll
        for (int f = 0; f < 2; ++f) {
            int ob = s * 64 + mh * 32 + f * 16 + g * 4;
            float4 b2v = *(const float4*)&b2[ob];
            ushort4 res = *(const ushort4*)&l1[ploc * 128 + (ob ^ swz)];
            float bv[4] = {b2v.x, b2v.y, b2v.z, b2v.w};
            unsigned short rr[4] = {res.x, res.y, res.z, res.w};
            #pragma unroll
            for (int e = 0; e < 4; ++e) {
                float v = acc[f][e] + bf2f(rr[e]) + bv[e];
                out2[(size_t)(ob + e) * HW + pix] = v;
                lsum += v;
                lsq += v * v;
            }
        }
        if (s == 0) {
            __syncthreads();
            stage_write<5>(r, wbuf, t);
            __syncthreads();
        }
    }

    // ---- per-block stats partial (no atomics) ----
    #pragma unroll
    for (int s = 1; s < 64; s <<= 1) {
        lsum += __shfl_xor(lsum, s);
        lsq  += __shfl_xor(lsq, s);
    }
    if (lane == 0) { rs[w] = lsum; rs[4 + w] = lsq; }
    __syncthreads();
    if (t == 0)
        partials[blockIdx.x] = make_float2(rs[0] + rs[1] + rs[2] + rs[3],
                                           rs[4] + rs[5] + rs[6] + rs[7]);
}

// ---------------- kernel 4: global layernorm (in place), per-block partial reduce ----------------
// 1024 blocks x 256 thr, 8 floats (2 x float4) per thread.
__global__ void norm_kernel(float* __restrict__ out2, const float2* __restrict__ partials,
                            const float* __restrict__ gn_w, const float* __restrict__ gn_b) {
    __shared__ float rs[8];
    __shared__ float stat[2];
    const int t = threadIdx.x;

    // redundant per-block reduction of the 512 partials (4 KB, L2-hot)
    float2 p0 = partials[t];
    float2 p1 = partials[t + 256];
    float a = p0.x + p1.x, bb = p0.y + p1.y;
    #pragma unroll
    for (int s = 1; s < 64; s <<= 1) {
        a  += __shfl_xor(a, s);
        bb += __shfl_xor(bb, s);
    }
    if ((t & 63) == 0) { rs[t >> 6] = a; rs[4 + (t >> 6)] = bb; }
    __syncthreads();
    if (t == 0) {
        const float invN = 1.f / 2097152.f;
        float mean = (rs[0] + rs[1] + rs[2] + rs[3]) * invN;
        float var = (rs[4] + rs[5] + rs[6] + rs[7]) * invN - mean * mean;
        stat[0] = mean;
        stat[1] = rsqrtf(var + 1e-5f);
    }
    __syncthreads();

    const float mean = stat[0], rstd = stat[1];
    const size_t base = ((size_t)blockIdx.x * 256 + t) * 8;
    int o = (int)(base >> 14);    // / HW (8 | HW so one channel per thread-chunk)
    float g = gn_w[o] * rstd;
    float b = gn_b[o];
    float4 v0 = *(const float4*)(out2 + base);
    float4 v1 = *(const float4*)(out2 + base + 4);
    float4 r0, r1;
    r0.x = (v0.x - mean) * g + b;
    r0.y = (v0.y - mean) * g + b;
    r0.z = (v0.z - mean) * g + b;
    r0.w = (v0.w - mean) * g + b;
    r1.x = (v1.x - mean) * g + b;
    r1.y = (v1.y - mean) * g + b;
    r1.z = (v1.z - mean) * g + b;
    r1.w = (v1.w - mean) * g + b;
    *(float4*)(out2 + base) = r0;
    *(float4*)(out2 + base + 4) = r1;
}

extern "C" void kernel_launch(void* const* d_in, const int* in_sizes, int n_in,
                              void* d_out, int out_size, void* d_ws, size_t ws_size,
                              hipStream_t stream) {
    const float* query  = (const float*)d_in[0];
    const float* key    = (const float*)d_in[1];
    const float* value  = (const float*)d_in[2];
    const float* deform = (const float*)d_in[3];
    const float* w_q    = (const float*)d_in[4];
    const float* w_k    = (const float*)d_in[5];
    const float* w_v    = (const float*)d_in[6];
    const float* w_fc   = (const float*)d_in[7];
    const float* mlp_w1 = (const float*)d_in[8];
    const float* mlp_b1 = (const float*)d_in[9];
    const float* mlp_w2 = (const float*)d_in[10];
    const float* mlp_b2 = (const float*)d_in[11];
    const float* gn_w   = (const float*)d_in[12];
    const float* gn_b   = (const float*)d_in[13];

    float* out = (float*)d_out;
    char* wsb  = (char*)d_ws;

    // ws layout (bytes): q_t bf16 [0,4M) | kv_t bf16 [4M,12M) | ao bf16 [12M,16M)
    //                    | wb bf16 [16M,+192K) | partials [17M, +4K)
    unsigned short* q_t  = (unsigned short*)wsb;
    unsigned short* kv_t = (unsigned short*)(wsb + ((size_t)4 << 20));
    unsigned short* ao_t = (unsigned short*)(wsb + ((size_t)12 << 20));
    unsigned short* wb   = (unsigned short*)(wsb + ((size_t)16 << 20));
    float2* partials = (float2*)(wsb + ((size_t)17 << 20));

    qkv_mfma<<<512, 256, 0, stream>>>(query, key, value, w_q, w_k, w_v,
                                      w_fc, mlp_w1, mlp_w2, wb, q_t, kv_t);
    attn_kernel<<<1024, 256, 0, stream>>>(q_t, kv_t, deform, ao_t);
    mlp_mfma<<<512, 256, 0, stream>>>(ao_t, wb, mlp_b1, mlp_b2, out, partials);
    norm_kernel<<<1024, 256, 0, stream>>>(out, partials, gn_w, gn_b);
}